// Round 1
// baseline (423.788 us; speedup 1.0000x reference)
//
#include <hip/hip_runtime.h>
#include <math.h>

typedef _Float16 f16;
typedef f16 f16x4 __attribute__((ext_vector_type(4)));
typedef f16 f16x8 __attribute__((ext_vector_type(8)));
typedef float f32x4 __attribute__((ext_vector_type(4)));

#define TOKENS 8192
#define EXPERTS 256
#define KDIM 7168
#define BM 128
#define BN 256
#define BK 32
#define SPLITK 4
#define KCHUNK (KDIM / SPLITK)   // 1792
#define NSTEP (KCHUNK / BK)      // 56
#define APAD 40                  // padded LDS row (f16 elems): breaks bank conflicts

#define XSCALE 256.0f
#define WSCALE 4096.0f

__device__ __forceinline__ void cvt4(const float4 v, const float scale, f16x4* hi, f16x4* lo) {
  float a = v.x * scale, b = v.y * scale, c = v.z * scale, d = v.w * scale;
  f16 ha = (f16)a, hb = (f16)b, hc = (f16)c, hd = (f16)d;
  f16x4 h, l;
  h.x = ha; h.y = hb; h.z = hc; h.w = hd;
  l.x = (f16)(a - (float)ha);
  l.y = (f16)(b - (float)hb);
  l.z = (f16)(c - (float)hc);
  l.w = (f16)(d - (float)hd);
  *hi = h; *lo = l;
}

// C[t][e] = sum_k x[t][k] * w[e][k], via fp16 2-split (3 MFMA products), K split 4-way,
// partials accumulated with atomicAdd into pre-zeroed logits buffer.
__global__ __launch_bounds__(512, 2) void router_gemm(const float* __restrict__ x,
                                                      const float* __restrict__ w,
                                                      float* __restrict__ logits) {
  __shared__ f16 Ah[BM][APAD], Al[BM][APAD];
  __shared__ f16 Bh[BN][APAD], Bl[BN][APAD];

  const int tid = threadIdx.x;
  const int mtile = blockIdx.x >> 2;   // 0..63
  const int ks = blockIdx.x & 3;       // K-split id
  const int m0 = mtile * BM;
  const int k0 = ks * KCHUNK;

  const int lane = tid & 63;
  const int wv = tid >> 6;   // 0..7
  const int wm = wv >> 2;    // 0..1  (wave row)
  const int wn = wv & 3;     // 0..3  (wave col)
  const int fr = lane & 15;
  const int fq = lane >> 4;

  f32x4 acc0[4][4];  // hi*hi
  f32x4 accX[4][4];  // cross terms (separate acc: negligible rounding at 2^-12 scale)
#pragma unroll
  for (int i = 0; i < 4; ++i)
#pragma unroll
    for (int j = 0; j < 4; ++j) {
      acc0[i][j] = (f32x4){0.f, 0.f, 0.f, 0.f};
      accX[i][j] = (f32x4){0.f, 0.f, 0.f, 0.f};
    }

  // staging addressing: 8 threads per row, one float4 each (32 floats = BK)
  const int arow0 = tid >> 3;  // 0..63
  const int ac4 = tid & 7;
  const float* xp = x + (size_t)(m0 + arow0) * KDIM + k0 + ac4 * 4;
  const float* wp = w + (size_t)arow0 * KDIM + k0 + ac4 * 4;

  float4 ra[2], rb[4];
#pragma unroll
  for (int i = 0; i < 2; ++i) ra[i] = *(const float4*)(xp + (size_t)(64 * i) * KDIM);
#pragma unroll
  for (int i = 0; i < 4; ++i) rb[i] = *(const float4*)(wp + (size_t)(64 * i) * KDIM);

  for (int step = 0; step < NSTEP; ++step) {
    __syncthreads();
    // convert fp32 -> (hi,lo) fp16 and write LDS
#pragma unroll
    for (int i = 0; i < 2; ++i) {
      f16x4 h, l;
      cvt4(ra[i], XSCALE, &h, &l);
      const int row = arow0 + 64 * i;
      *(f16x4*)&Ah[row][ac4 * 4] = h;
      *(f16x4*)&Al[row][ac4 * 4] = l;
    }
#pragma unroll
    for (int i = 0; i < 4; ++i) {
      f16x4 h, l;
      cvt4(rb[i], WSCALE, &h, &l);
      const int row = arow0 + 64 * i;
      *(f16x4*)&Bh[row][ac4 * 4] = h;
      *(f16x4*)&Bl[row][ac4 * 4] = l;
    }
    __syncthreads();
    // register prefetch of next tile (overlaps with MFMA below)
    if (step + 1 < NSTEP) {
      const float* xq = xp + (step + 1) * BK;
      const float* wq = wp + (step + 1) * BK;
#pragma unroll
      for (int i = 0; i < 2; ++i) ra[i] = *(const float4*)(xq + (size_t)(64 * i) * KDIM);
#pragma unroll
      for (int i = 0; i < 4; ++i) rb[i] = *(const float4*)(wq + (size_t)(64 * i) * KDIM);
    }
    // fragments: row = lane&15, k-octet = lane>>4 (16B contiguous reads)
    f16x8 fa_h[4], fa_l[4], fb_h[4], fb_l[4];
#pragma unroll
    for (int m = 0; m < 4; ++m) {
      const int row = wm * 64 + m * 16 + fr;
      fa_h[m] = *(const f16x8*)&Ah[row][fq * 8];
      fa_l[m] = *(const f16x8*)&Al[row][fq * 8];
    }
#pragma unroll
    for (int n = 0; n < 4; ++n) {
      const int row = wn * 64 + n * 16 + fr;
      fb_h[n] = *(const f16x8*)&Bh[row][fq * 8];
      fb_l[n] = *(const f16x8*)&Bl[row][fq * 8];
    }
#pragma unroll
    for (int m = 0; m < 4; ++m)
#pragma unroll
      for (int n = 0; n < 4; ++n) {
        acc0[m][n] = __builtin_amdgcn_mfma_f32_16x16x32_f16(fa_h[m], fb_h[n], acc0[m][n], 0, 0, 0);
        accX[m][n] = __builtin_amdgcn_mfma_f32_16x16x32_f16(fa_h[m], fb_l[n], accX[m][n], 0, 0, 0);
        accX[m][n] = __builtin_amdgcn_mfma_f32_16x16x32_f16(fa_l[m], fb_h[n], accX[m][n], 0, 0, 0);
      }
  }

  constexpr float inv = 1.0f / (XSCALE * WSCALE);  // 2^-20, exact
#pragma unroll
  for (int m = 0; m < 4; ++m)
#pragma unroll
    for (int n = 0; n < 4; ++n)
#pragma unroll
      for (int j = 0; j < 4; ++j) {
        const int row = m0 + wm * 64 + m * 16 + fq * 4 + j;  // C/D: row=(lane>>4)*4+reg
        const int col = wn * 64 + n * 16 + fr;               // col=lane&15
        atomicAdd(&logits[(size_t)row * EXPERTS + col], (acc0[m][n][j] + accX[m][n][j]) * inv);
      }
}

// One wave per token: sigmoid(double) + bias, group top-2 sums, top-4 groups,
// 8 rounds of wave-argmax with jax tie-breaking (equal value -> lower index).
__global__ __launch_bounds__(256) void router_select(const float* __restrict__ logits,
                                                     const float* __restrict__ bias,
                                                     float* __restrict__ out) {
  const int lane = threadIdx.x & 63;
  const int t = (blockIdx.x << 2) + (threadIdx.x >> 6);

  const float4 lg = reinterpret_cast<const float4*>(logits)[(size_t)t * 64 + lane];
  const float4 bb = reinterpret_cast<const float4*>(bias)[lane];

  const float s0 = (float)(1.0 / (1.0 + exp(-(double)lg.x)));
  const float s1 = (float)(1.0 / (1.0 + exp(-(double)lg.y)));
  const float s2 = (float)(1.0 / (1.0 + exp(-(double)lg.z)));
  const float s3 = (float)(1.0 / (1.0 + exp(-(double)lg.w)));
  const float b0 = s0 + bb.x, b1 = s1 + bb.y, b2 = s2 + bb.z, b3 = s3 + bb.w;

  // per-lane top2 (values only; sum is tie-order invariant)
  float v1 = b0, v2 = -1e30f;
  if (b1 > v1) { v2 = v1; v1 = b1; } else if (b1 > v2) v2 = b1;
  if (b2 > v1) { v2 = v1; v1 = b2; } else if (b2 > v2) v2 = b2;
  if (b3 > v1) { v2 = v1; v1 = b3; } else if (b3 > v2) v2 = b3;
  // merge across the 8 lanes of this group
#pragma unroll
  for (int d = 1; d < 8; d <<= 1) {
    const float o1 = __shfl_xor(v1, d), o2 = __shfl_xor(v2, d);
    const float n1 = fmaxf(v1, o1);
    const float n2 = fmaxf(fminf(v1, o1), fmaxf(v2, o2));
    v1 = n1; v2 = n2;
  }
  const float gs = v1 + v2;

  const float gv0 = __shfl(gs, 0),  gv1 = __shfl(gs, 8),  gv2 = __shfl(gs, 16), gv3 = __shfl(gs, 24);
  const float gv4 = __shfl(gs, 32), gv5 = __shfl(gs, 40), gv6 = __shfl(gs, 48), gv7 = __shfl(gs, 56);

  unsigned sel = 0;
#pragma unroll
  for (int it = 0; it < 4; ++it) {
    float bvv = -1e30f; int bg = 0;
    if (!(sel & 1u)   && gv0 > bvv) { bvv = gv0; bg = 0; }
    if (!(sel & 2u)   && gv1 > bvv) { bvv = gv1; bg = 1; }
    if (!(sel & 4u)   && gv2 > bvv) { bvv = gv2; bg = 2; }
    if (!(sel & 8u)   && gv3 > bvv) { bvv = gv3; bg = 3; }
    if (!(sel & 16u)  && gv4 > bvv) { bvv = gv4; bg = 4; }
    if (!(sel & 32u)  && gv5 > bvv) { bvv = gv5; bg = 5; }
    if (!(sel & 64u)  && gv6 > bvv) { bvv = gv6; bg = 6; }
    if (!(sel & 128u) && gv7 > bvv) { bvv = gv7; bg = 7; }
    sel |= (1u << bg);
  }

  const bool keep = (sel >> (lane >> 3)) & 1u;
  float c0 = keep ? b0 : -1e30f, c1 = keep ? b1 : -1e30f;
  float c2 = keep ? b2 : -1e30f, c3 = keep ? b3 : -1e30f;

  float wsum = 0.0f, myw = 0.0f;
  int myi = 0;
#pragma unroll
  for (int rnd = 0; rnd < 8; ++rnd) {
    float bv = c0; int bj = 0;
    if (c1 > bv) { bv = c1; bj = 1; }
    if (c2 > bv) { bv = c2; bj = 2; }
    if (c3 > bv) { bv = c3; bj = 3; }
    float bs = (bj == 0) ? s0 : (bj == 1) ? s1 : (bj == 2) ? s2 : s3;
    int bi = (lane << 2) | bj;
#pragma unroll
    for (int d = 1; d < 64; d <<= 1) {
      const float ov = __shfl_xor(bv, d);
      const int oi = __shfl_xor(bi, d);
      const float os = __shfl_xor(bs, d);
      if (ov > bv || (ov == bv && oi < bi)) { bv = ov; bi = oi; bs = os; }
    }
    wsum += bs;
    if (lane == rnd) { myw = bs; myi = bi; }
    if ((bi >> 2) == lane) {
      const int jj = bi & 3;
      if (jj == 0) c0 = -1e30f;
      else if (jj == 1) c1 = -1e30f;
      else if (jj == 2) c2 = -1e30f;
      else c3 = -1e30f;
    }
  }

  if (lane < 8) {
    out[(size_t)t * 8 + lane] = myw * 2.5f / wsum;
    out[(size_t)TOKENS * 8 + (size_t)t * 8 + lane] = (float)myi;  // indices as float
  }
}

extern "C" void kernel_launch(void* const* d_in, const int* in_sizes, int n_in,
                              void* d_out, int out_size, void* d_ws, size_t ws_size,
                              hipStream_t stream) {
  const float* x = (const float*)d_in[0];
  const float* w = (const float*)d_in[1];
  const float* bias = (const float*)d_in[2];
  float* out = (float*)d_out;
  float* logits = (float*)d_ws;

  hipMemsetAsync(logits, 0, (size_t)TOKENS * EXPERTS * sizeof(float), stream);
  router_gemm<<<dim3(64 * SPLITK), dim3(512), 0, stream>>>(x, w, logits);
  router_select<<<dim3(TOKENS / 4), dim3(256), 0, stream>>>(logits, bias, out);
}